// Round 8
// baseline (310.867 us; speedup 1.0000x reference)
//
#include <hip/hip_runtime.h>

// CNN self-attention: B=4, C=256, H=W=64 -> N=4096.
// Round 8: deferred-PV with SAFE buffering: step i = QK(i) || PV(i-1) in one
//          MFMA burst; K dbuf + V TRIPLE-buf so every DMA write is >=2 barriers
//          after the buffer's last read (6-step unroll makes indices static).
//          One vmcnt(0)+s_barrier+sched_barrier per step. exp2-domain softmax,
//          defer-rescale THR=12. Projection/combine verbatim from passed rounds.
// Workspace: Qh,Kh,Vt f16 (24MB) + Op f16 (32MB) + stats (512KB) + Wh (384KB).

typedef _Float16 f16;
typedef f16 f16x4 __attribute__((ext_vector_type(4)));
typedef f16 f16x8 __attribute__((ext_vector_type(8)));
typedef float f32x16 __attribute__((ext_vector_type(16)));

#define NB 4
#define NC 256
#define NN 4096
#define KVSPLIT 4
#define KRANGE (NN / KVSPLIT)   // 1024 keys per split
#define NCHUNK (KRANGE / 32)    // 32 chunks of 32 keys

typedef const __attribute__((address_space(1))) void* gas_t;
typedef __attribute__((address_space(3))) void* las_t;

__device__ __forceinline__ void load_lds16(const void* g, void* l) {
    // async global->LDS DMA: LDS dest = uniform base + lane*16 (linear)
    __builtin_amdgcn_global_load_lds((gas_t)g, (las_t)l, 16, 0, 0);
}

// ---------------- Kernel 0: W fp32 -> f16 ----------------
__global__ __launch_bounds__(256) void wcvt_kernel(
    const float* __restrict__ Wq, const float* __restrict__ Wk,
    const float* __restrict__ Wv, f16* __restrict__ Wh)
{
    const int idx = blockIdx.x * 256 + threadIdx.x;   // grid = 768 blocks
    const float* s = (idx < 65536) ? Wq : (idx < 131072 ? Wk : Wv);
    Wh[idx] = (f16)s[idx & 65535];
}

// ---------------- Kernel 1: QKV projection via MFMA ----------------
// (validated rounds 2-6; Q scaled by log2(e) for exp2-domain softmax)
__global__ __launch_bounds__(256) void qkv_mfma_kernel(
    const float* __restrict__ x, const f16* __restrict__ Wh,
    const float* __restrict__ bq, const float* __restrict__ bk, const float* __restrict__ bv,
    f16* __restrict__ Qh, f16* __restrict__ Kh, f16* __restrict__ Vt)
{
    const int b  = blockIdx.y;
    const int n0 = blockIdx.x * 64;
    const int t  = threadIdx.x;
    const int wv = t >> 6, l = t & 63, ln = l & 31, g = l >> 5;

    __shared__ char xs[64 * 512];   // x^T tile [n][ci], swizzled granules
    __shared__ char st[32768];      // output staging

    {
        const int ci0 = t >> 4;
        const int nq  = (t & 15) * 4;
        for (int it = 0; it < 16; ++it) {
            const int ci = it * 16 + ci0;
            float v4[4];
            *(float4*)v4 = *(const float4*)(x + ((size_t)b * NC + ci) * NN + n0 + nq);
            const int gr = ci >> 3, lo = (ci & 7) * 2;
            #pragma unroll
            for (int j = 0; j < 4; ++j) {
                const int n = nq + j;
                *(f16*)(xs + n * 512 + ((gr ^ (n & 7)) * 16 + lo)) = (f16)v4[j];
            }
        }
    }
    __syncthreads();

    const int c0 = wv * 64;
    for (int m = 0; m < 3; ++m) {
        const f16*  W    = Wh + m * (NC * NC);
        const float* bias = (m == 0) ? bq : (m == 1 ? bk : bv);
        const float qs   = (m == 0) ? 1.44269504f : 1.0f;

        f32x16 acc[2][2];
        #pragma unroll
        for (int i = 0; i < 2; ++i)
            #pragma unroll
            for (int j = 0; j < 2; ++j)
                #pragma unroll
                for (int r = 0; r < 16; ++r) acc[i][j][r] = 0.0f;

        #pragma unroll
        for (int cs = 0; cs < 16; ++cs) {
            f16x8 a0 = *(const f16x8*)(W + (size_t)(c0 + ln) * NC + cs * 16 + 8 * g);
            f16x8 a1 = *(const f16x8*)(W + (size_t)(c0 + 32 + ln) * NC + cs * 16 + 8 * g);
            const int xb = (cs * 32 + g * 16) ^ ((ln & 7) << 4);
            f16x8 b0 = *(const f16x8*)(xs + ln * 512 + xb);
            f16x8 b1 = *(const f16x8*)(xs + (32 + ln) * 512 + xb);
            acc[0][0] = __builtin_amdgcn_mfma_f32_32x32x16_f16(a0, b0, acc[0][0], 0, 0, 0);
            acc[0][1] = __builtin_amdgcn_mfma_f32_32x32x16_f16(a0, b1, acc[0][1], 0, 0, 0);
            acc[1][0] = __builtin_amdgcn_mfma_f32_32x32x16_f16(a1, b0, acc[1][0], 0, 0, 0);
            acc[1][1] = __builtin_amdgcn_mfma_f32_32x32x16_f16(a1, b1, acc[1][1], 0, 0, 0);
        }

        __syncthreads();
        if (m < 2) {
            #pragma unroll
            for (int ct = 0; ct < 2; ++ct)
                #pragma unroll
                for (int nt = 0; nt < 2; ++nt)
                    #pragma unroll
                    for (int q = 0; q < 4; ++q) {
                        const int cb = c0 + ct * 32 + 8 * q + 4 * g;
                        f16x4 pk;
                        #pragma unroll
                        for (int j = 0; j < 4; ++j)
                            pk[j] = (f16)((acc[ct][nt][q * 4 + j] + bias[cb + j]) * qs);
                        const int n  = nt * 32 + ln;
                        const int g8 = cb >> 3;
                        *(f16x4*)(st + n * 512 + ((g8 ^ (n & 7)) * 16 + (cb & 7) * 2)) = pk;
                    }
            __syncthreads();
            f16* dst = (m == 0) ? Qh : Kh;
            const int gi  = t & 31;
            const int nb8 = (t >> 5) * 8;
            #pragma unroll
            for (int k = 0; k < 8; ++k) {
                const int n = nb8 + k;
                const uint4 d = *(const uint4*)(st + n * 512 + ((gi ^ (n & 7)) << 4));
                *(uint4*)(dst + ((size_t)b * NN + n0 + n) * NC + gi * 8) = d;
            }
        } else {
            #pragma unroll
            for (int ct = 0; ct < 2; ++ct)
                #pragma unroll
                for (int nt = 0; nt < 2; ++nt) {
                    const int n  = nt * 32 + ln;
                    const int pn = (n & ~15) | (n & 3) | ((n & 8) >> 1) | ((n & 4) << 1);
                    #pragma unroll
                    for (int r = 0; r < 16; ++r) {
                        const int c = c0 + ct * 32 + (r & 3) + 8 * (r >> 2) + 4 * g;
                        *(f16*)(st + c * 128 + ((pn * 2) ^ ((c & 7) << 4))) =
                            (f16)(acc[ct][nt][r] + bias[c]);
                    }
                }
            __syncthreads();
            #pragma unroll
            for (int ci = 0; ci < 8; ++ci) {
                const int c = ci * 32 + (t >> 3);
                const int s = t & 7;
                const uint4 d = *(const uint4*)(st + c * 128 + ((s ^ (c & 7)) << 4));
                *(uint4*)(Vt + ((size_t)b * NC + c) * NN + n0 + s * 8) = d;
            }
        }
    }
}

// ---------------- Kernel 2: MFMA flash attention (deferred-PV, safe bufs) ----
// 512 blocks x 256 thr = 2 blocks/CU. LDS: K 2x16KB, V 3x16KB = 80KB.
// Step i: vmcnt(0) [drains DMA(i), issued one step ago] -> s_barrier ->
// sched_barrier -> DMA(i+1) -> setprio{ QK(i) + PV(i-1) } -> SM(i).
// Every buffer overwrite is >= 2 barrier-phases after its last read.
__global__ __launch_bounds__(256, 2) void flash_mfma_kernel(
    const f16* __restrict__ Qh, const f16* __restrict__ Kh, const f16* __restrict__ Vt,
    f16* __restrict__ Op, float* __restrict__ Mst, float* __restrict__ Lst)
{
    const int t  = threadIdx.x;
    const int wv = t >> 6;         // 0..3
    const int l  = t & 63;
    const int ln = l & 31;
    const int g  = l >> 5;

    // XCD swizzle: 2 (b,split) KV streams per XCD, 32 q-tile blocks per stream.
    const int flat  = blockIdx.x;        // 0..511
    const int xcd   = flat & 7;
    const int idx   = flat >> 3;         // 0..63
    const int bs    = xcd * 2 + (idx & 1);   // 0..15
    const int qt    = idx >> 1;          // 0..31
    const int b     = bs >> 2;
    const int split = bs & 3;
    const int qrow  = qt * 128 + wv * 32 + ln;

    __shared__ char ldsK[2 * 16384];   // [buf][32 key-rows x 512B], ^(row&15)
    __shared__ char ldsV[3 * 16384];   // [buf][64 rows x 256B] 4ch/row, ^(R&3)

    // ---- Q fragments (register-resident) ----
    f16x8 qf[16];
    {
        const f16* Qb = Qh + ((size_t)b * NN + qrow) * NC;
        #pragma unroll
        for (int cs = 0; cs < 16; ++cs)
            qf[cs] = *(const f16x8*)(Qb + cs * 16 + 8 * g);
    }

    f32x16 o[8];
    #pragma unroll
    for (int ct = 0; ct < 8; ++ct)
        #pragma unroll
        for (int r = 0; r < 16; ++r) o[ct][r] = 0.0f;

    float mrun = -1e30f, lrun = 0.0f;
    f16x8 pfA[2], pfB[2];
    f32x16 s;
    const int key_base = split * KRANGE;
    const f16* KhB = Kh + (size_t)b * NN * NC;
    const f16* VtB = Vt + (size_t)b * NC * NN;

    // DMA chunk CH: K -> ldsK[KB], V -> ldsV[VB]  (8 loads / wave)
#define DMA(CH, KB, VB) do {                                                         \
        const int key0_ = key_base + (CH) * 32;                                      \
        _Pragma("unroll")                                                            \
        for (int j = 0; j < 4; ++j) {                                                \
            const int r2  = wv * 4 + j;                                              \
            const int row = r2 * 2 + (l >> 5);                                       \
            const int u   = (l & 31) ^ (row & 15);                                   \
            load_lds16(KhB + (size_t)(key0_ + row) * NC + u * 8,                     \
                       ldsK + (KB) * 16384 + r2 * 1024);                             \
        }                                                                            \
        _Pragma("unroll")                                                            \
        for (int j = 0; j < 4; ++j) {                                                \
            const int i_ = wv * 4 + j;                                               \
            const int R  = i_ * 4 + (l >> 4);                                        \
            const int c  = R * 4 + ((l & 15) >> 2);                                  \
            const int kg = (l & 3) ^ (R & 3);                                        \
            load_lds16(VtB + (size_t)c * NN + key0_ + kg * 8,                        \
                       ldsV + (VB) * 16384 + i_ * 1024);                             \
        }                                                                            \
    } while (0)

    // QK: S^T = K . Q^T (16 MFMAs into s)
#define QKC(KB) do {                                                                 \
        _Pragma("unroll")                                                            \
        for (int r = 0; r < 16; ++r) s[r] = 0.0f;                                    \
        const char* K0_ = ldsK + (KB) * 16384;                                       \
        _Pragma("unroll")                                                            \
        for (int cs = 0; cs < 16; ++cs) {                                            \
            const int col = ((cs * 2 + g) ^ (ln & 15)) * 16;                         \
            f16x8 a0 = *(const f16x8*)(K0_ + ln * 512 + col);                        \
            s = __builtin_amdgcn_mfma_f32_32x32x16_f16(a0, qf[cs], s, 0, 0, 0);      \
        }                                                                            \
    } while (0)

    // PV: O^T += V^T . P^T (16 MFMAs, 8 independent chains)
#define PVC(VB, PF) do {                                                             \
        const char* V0_ = ldsV + (VB) * 16384;                                       \
        _Pragma("unroll")                                                            \
        for (int ct = 0; ct < 8; ++ct) {                                             \
            const int c    = ct * 32 + ln;                                           \
            const int base = (c >> 2) * 256 + (c & 3) * 64;                          \
            const int rsw  = (c >> 2) & 3;                                           \
            _Pragma("unroll")                                                        \
            for (int ss = 0; ss < 2; ++ss) {                                         \
                f16x8 va = *(const f16x8*)(V0_ + base + (((ss * 2 + g) ^ rsw) * 16));\
                o[ct] = __builtin_amdgcn_mfma_f32_32x32x16_f16(va, PF[ss], o[ct], 0, 0, 0); \
            }                                                                        \
        }                                                                            \
    } while (0)

    // online softmax, exp2 domain, defer-rescale THR=12 (p <= 2^12, f16-safe)
#define SM(PFOUT) do {                                                               \
        float mt = s[0];                                                             \
        _Pragma("unroll")                                                            \
        for (int r = 1; r < 16; ++r) mt = fmaxf(mt, s[r]);                           \
        mt = fmaxf(mt, __shfl_xor(mt, 32));                                          \
        if (!__all(mt <= mrun + 12.0f)) {                                            \
            const float mnew  = fmaxf(mrun, mt);                                     \
            const float alpha = exp2f(mrun - mnew);                                  \
            _Pragma("unroll")                                                        \
            for (int ct = 0; ct < 8; ++ct)                                           \
                _Pragma("unroll")                                                    \
                for (int r = 0; r < 16; ++r) o[ct][r] *= alpha;                      \
            lrun *= alpha;                                                           \
            mrun  = mnew;                                                            \
        }                                                                            \
        float ps = 0.0f;                                                             \
        _Pragma("unroll")                                                            \
        for (int r = 0; r < 16; ++r) {                                               \
            const float e0 = exp2f(s[r] - mrun);                                     \
            ps += e0;                                                                \
            PFOUT[r >> 3][r & 7] = (f16)e0;                                          \
        }                                                                            \
        ps += __shfl_xor(ps, 32);                                                    \
        lrun += ps;                                                                  \
    } while (0)

    // Step CH (>=1): wait DMA(CH) -> barrier -> DMA(CH+1) -> QK(CH)+PV(CH-1) -> SM
#define STEP(CH, KBR, VBR, KBW, VBW, PFIN, PFOUT, PREF) do {                         \
        asm volatile("s_waitcnt vmcnt(0)" ::: "memory");                             \
        __builtin_amdgcn_s_barrier();                                                \
        __builtin_amdgcn_sched_barrier(0);                                           \
        if (PREF) DMA((CH) + 1, KBW, VBW);                                           \
        __builtin_amdgcn_s_setprio(1);                                               \
        QKC(KBR);                                                                    \
        PVC(VBR, PFIN);                                                              \
        __builtin_amdgcn_s_setprio(0);                                               \
        SM(PFOUT);                                                                   \
    } while (0)

    // ---- prologue: chunk 0 ----
    DMA(0, 0, 0);
    asm volatile("s_waitcnt vmcnt(0)" ::: "memory");   // DMA(0) landed (this wave)
    __builtin_amdgcn_s_barrier();                      // ... (all waves)
    __builtin_amdgcn_sched_barrier(0);
    DMA(1, 1, 1);
    __builtin_amdgcn_s_setprio(1);
    QKC(0);
    __builtin_amdgcn_s_setprio(0);
    SM(pfA);

    // ---- steps 1..30: 5 x 6-step unroll (K parity 2, V parity 3) ----
    for (int k = 0; k < 5; ++k) {
        const int base = 1 + k * 6;
        STEP(base + 0, 1, 0, 0, 2, pfA, pfB, 1);
        STEP(base + 1, 0, 1, 1, 0, pfB, pfA, 1);
        STEP(base + 2, 1, 2, 0, 1, pfA, pfB, 1);
        STEP(base + 3, 0, 0, 1, 2, pfB, pfA, 1);
        STEP(base + 4, 1, 1, 0, 0, pfA, pfB, 1);
        STEP(base + 5, 0, 2, 1, 1, pfB, pfA, 1);
    }
    // ---- step 31 (no prefetch) ----
    STEP(31, 1, 0, 0, 0, pfA, pfB, 0);
    // ---- drain: PV(31) from Vbuf[31 % 3 = 1]; nothing outstanding ----
    __builtin_amdgcn_s_setprio(1);
    PVC(1, pfB);
    __builtin_amdgcn_s_setprio(0);

#undef STEP
#undef SM
#undef PVC
#undef QKC
#undef DMA

    // ---- epilogue: normalized partial (f16) + stats (log2-domain m) ----
    const float invl = 1.0f / lrun;
    #pragma unroll
    for (int ct = 0; ct < 8; ++ct)
        #pragma unroll
        for (int r = 0; r < 16; ++r) {
            const int c = ct * 32 + (r & 3) + 8 * (r >> 2) + 4 * g;
            Op[((size_t)(split * NB + b) * NC + c) * NN + qrow] = (f16)(o[ct][r] * invl);
        }
    if (g == 0) {
        Mst[(split * NB + b) * NN + qrow] = mrun;
        Lst[(split * NB + b) * NN + qrow] = lrun;
    }
}

// ---------------- Kernel 3: combine kv-split partials ----------------
__global__ __launch_bounds__(256) void combine_kernel(
    const f16* __restrict__ Op, const float* __restrict__ Mst, const float* __restrict__ Lst,
    float* __restrict__ out)
{
    const int t = threadIdx.x;
    const int b = blockIdx.y;
    const int n = blockIdx.x * 64 + (t & 63);

    float w[KVSPLIT];
    float mm = -1e30f;
    #pragma unroll
    for (int s = 0; s < KVSPLIT; ++s) {
        w[s] = Mst[(s * NB + b) * NN + n];
        mm = fmaxf(mm, w[s]);
    }
    float tot = 0.0f;
    #pragma unroll
    for (int s = 0; s < KVSPLIT; ++s) {
        w[s] = exp2f(w[s] - mm) * Lst[(s * NB + b) * NN + n];
        tot += w[s];
    }
    const float inv = 1.0f / tot;
    #pragma unroll
    for (int s = 0; s < KVSPLIT; ++s) w[s] *= inv;

    for (int c = (t >> 6); c < NC; c += 4) {
        float acc = 0.0f;
        #pragma unroll
        for (int s = 0; s < KVSPLIT; ++s)
            acc += w[s] * (float)Op[((size_t)(s * NB + b) * NC + c) * NN + n];
        out[((size_t)b * NC + c) * NN + n] = acc;
    }
}

extern "C" void kernel_launch(void* const* d_in, const int* in_sizes, int n_in,
                              void* d_out, int out_size, void* d_ws, size_t ws_size,
                              hipStream_t stream)
{
    const float* x  = (const float*)d_in[0];
    const float* Wq = (const float*)d_in[1];
    const float* Wk = (const float*)d_in[2];
    const float* Wv = (const float*)d_in[3];
    const float* bq = (const float*)d_in[4];
    const float* bk = (const float*)d_in[5];
    const float* bv = (const float*)d_in[6];
    float* out = (float*)d_out;

    // Workspace layout (~57 MB)
    f16* Qh = (f16*)d_ws;                                       // 8 MB
    f16* Kh = Qh + (size_t)NB * NN * NC;                        // 8 MB
    f16* Vt = Kh + (size_t)NB * NN * NC;                        // 8 MB
    f16* Op = Vt + (size_t)NB * NN * NC;                        // 32 MB
    float* Mst = (float*)(Op + (size_t)KVSPLIT * NB * NC * NN); // 256 KB
    float* Lst = Mst + (size_t)KVSPLIT * NB * NN;               // 256 KB
    f16*  Wh  = (f16*)(Lst + (size_t)KVSPLIT * NB * NN);        // 384 KB

    wcvt_kernel<<<768, 256, 0, stream>>>(Wq, Wk, Wv, Wh);
    qkv_mfma_kernel<<<dim3(NN / 64, NB), 256, 0, stream>>>(
        x, Wh, bq, bk, bv, Qh, Kh, Vt);
    flash_mfma_kernel<<<512, 256, 0, stream>>>(Qh, Kh, Vt, Op, Mst, Lst);
    combine_kernel<<<dim3(NN / 64, NB), 256, 0, stream>>>(Op, Mst, Lst, out);
}

// Round 9
// 167.668 us; speedup vs baseline: 1.8541x; 1.8541x over previous
//
#include <hip/hip_runtime.h>

// CNN self-attention: B=4, C=256, H=W=64 -> N=4096.
// Round 9: R5 memory schedule byte-for-byte (distance-1 DMA, counted vmcnt(8),
//          2-barrier step, XCD swizzle) + critical-path cuts inside the step:
//          QK as 2 independent 8-chains (sa/sb), tree-max softmax, per-lane
//          partial lrun (single epilogue merge). exp2 domain, THR=12.
// Workspace: Qh,Kh,Vt f16 (24MB) + Op f16 (32MB) + stats (512KB) + Wh (384KB).

typedef _Float16 f16;
typedef f16 f16x4 __attribute__((ext_vector_type(4)));
typedef f16 f16x8 __attribute__((ext_vector_type(8)));
typedef float f32x16 __attribute__((ext_vector_type(16)));

#define NB 4
#define NC 256
#define NN 4096
#define KVSPLIT 4
#define KRANGE (NN / KVSPLIT)   // 1024 keys per split
#define NCHUNK (KRANGE / 32)    // 32 chunks of 32 keys

typedef const __attribute__((address_space(1))) void* gas_t;
typedef __attribute__((address_space(3))) void* las_t;

__device__ __forceinline__ void load_lds16(const void* g, void* l) {
    // async global->LDS DMA: LDS dest = uniform base + lane*16 (linear)
    __builtin_amdgcn_global_load_lds((gas_t)g, (las_t)l, 16, 0, 0);
}

// ---------------- Kernel 0: W fp32 -> f16 ----------------
__global__ __launch_bounds__(256) void wcvt_kernel(
    const float* __restrict__ Wq, const float* __restrict__ Wk,
    const float* __restrict__ Wv, f16* __restrict__ Wh)
{
    const int idx = blockIdx.x * 256 + threadIdx.x;   // grid = 768 blocks
    const float* s = (idx < 65536) ? Wq : (idx < 131072 ? Wk : Wv);
    Wh[idx] = (f16)s[idx & 65535];
}

// ---------------- Kernel 1: QKV projection via MFMA ----------------
// (validated rounds 2-8; Q scaled by log2(e) for exp2-domain softmax)
__global__ __launch_bounds__(256) void qkv_mfma_kernel(
    const float* __restrict__ x, const f16* __restrict__ Wh,
    const float* __restrict__ bq, const float* __restrict__ bk, const float* __restrict__ bv,
    f16* __restrict__ Qh, f16* __restrict__ Kh, f16* __restrict__ Vt)
{
    const int b  = blockIdx.y;
    const int n0 = blockIdx.x * 64;
    const int t  = threadIdx.x;
    const int wv = t >> 6, l = t & 63, ln = l & 31, g = l >> 5;

    __shared__ char xs[64 * 512];   // x^T tile [n][ci], swizzled granules
    __shared__ char st[32768];      // output staging

    {
        const int ci0 = t >> 4;
        const int nq  = (t & 15) * 4;
        for (int it = 0; it < 16; ++it) {
            const int ci = it * 16 + ci0;
            float v4[4];
            *(float4*)v4 = *(const float4*)(x + ((size_t)b * NC + ci) * NN + n0 + nq);
            const int gr = ci >> 3, lo = (ci & 7) * 2;
            #pragma unroll
            for (int j = 0; j < 4; ++j) {
                const int n = nq + j;
                *(f16*)(xs + n * 512 + ((gr ^ (n & 7)) * 16 + lo)) = (f16)v4[j];
            }
        }
    }
    __syncthreads();

    const int c0 = wv * 64;
    for (int m = 0; m < 3; ++m) {
        const f16*  W    = Wh + m * (NC * NC);
        const float* bias = (m == 0) ? bq : (m == 1 ? bk : bv);
        const float qs   = (m == 0) ? 1.44269504f : 1.0f;

        f32x16 acc[2][2];
        #pragma unroll
        for (int i = 0; i < 2; ++i)
            #pragma unroll
            for (int j = 0; j < 2; ++j)
                #pragma unroll
                for (int r = 0; r < 16; ++r) acc[i][j][r] = 0.0f;

        #pragma unroll
        for (int cs = 0; cs < 16; ++cs) {
            f16x8 a0 = *(const f16x8*)(W + (size_t)(c0 + ln) * NC + cs * 16 + 8 * g);
            f16x8 a1 = *(const f16x8*)(W + (size_t)(c0 + 32 + ln) * NC + cs * 16 + 8 * g);
            const int xb = (cs * 32 + g * 16) ^ ((ln & 7) << 4);
            f16x8 b0 = *(const f16x8*)(xs + ln * 512 + xb);
            f16x8 b1 = *(const f16x8*)(xs + (32 + ln) * 512 + xb);
            acc[0][0] = __builtin_amdgcn_mfma_f32_32x32x16_f16(a0, b0, acc[0][0], 0, 0, 0);
            acc[0][1] = __builtin_amdgcn_mfma_f32_32x32x16_f16(a0, b1, acc[0][1], 0, 0, 0);
            acc[1][0] = __builtin_amdgcn_mfma_f32_32x32x16_f16(a1, b0, acc[1][0], 0, 0, 0);
            acc[1][1] = __builtin_amdgcn_mfma_f32_32x32x16_f16(a1, b1, acc[1][1], 0, 0, 0);
        }

        __syncthreads();
        if (m < 2) {
            #pragma unroll
            for (int ct = 0; ct < 2; ++ct)
                #pragma unroll
                for (int nt = 0; nt < 2; ++nt)
                    #pragma unroll
                    for (int q = 0; q < 4; ++q) {
                        const int cb = c0 + ct * 32 + 8 * q + 4 * g;
                        f16x4 pk;
                        #pragma unroll
                        for (int j = 0; j < 4; ++j)
                            pk[j] = (f16)((acc[ct][nt][q * 4 + j] + bias[cb + j]) * qs);
                        const int n  = nt * 32 + ln;
                        const int g8 = cb >> 3;
                        *(f16x4*)(st + n * 512 + ((g8 ^ (n & 7)) * 16 + (cb & 7) * 2)) = pk;
                    }
            __syncthreads();
            f16* dst = (m == 0) ? Qh : Kh;
            const int gi  = t & 31;
            const int nb8 = (t >> 5) * 8;
            #pragma unroll
            for (int k = 0; k < 8; ++k) {
                const int n = nb8 + k;
                const uint4 d = *(const uint4*)(st + n * 512 + ((gi ^ (n & 7)) << 4));
                *(uint4*)(dst + ((size_t)b * NN + n0 + n) * NC + gi * 8) = d;
            }
        } else {
            #pragma unroll
            for (int ct = 0; ct < 2; ++ct)
                #pragma unroll
                for (int nt = 0; nt < 2; ++nt) {
                    const int n  = nt * 32 + ln;
                    const int pn = (n & ~15) | (n & 3) | ((n & 8) >> 1) | ((n & 4) << 1);
                    #pragma unroll
                    for (int r = 0; r < 16; ++r) {
                        const int c = c0 + ct * 32 + (r & 3) + 8 * (r >> 2) + 4 * g;
                        *(f16*)(st + c * 128 + ((pn * 2) ^ ((c & 7) << 4))) =
                            (f16)(acc[ct][nt][r] + bias[c]);
                    }
                }
            __syncthreads();
            #pragma unroll
            for (int ci = 0; ci < 8; ++ci) {
                const int c = ci * 32 + (t >> 3);
                const int s = t & 7;
                const uint4 d = *(const uint4*)(st + c * 128 + ((s ^ (c & 7)) << 4));
                *(uint4*)(Vt + ((size_t)b * NC + c) * NN + n0 + s * 8) = d;
            }
        }
    }
}

// ---------------- Kernel 2: MFMA flash attention ----------------
// 512 blocks x 256 thr = 2 blocks/CU (independent barrier domains), 64KB LDS.
// Per chunk (R5 schedule): issue DMA(ch+1) -> vmcnt(8) [FIFO => chunk ch all
// landed] -> s_barrier -> QK(2 chains) -> SM -> PV -> s_barrier.
__global__ __launch_bounds__(256, 2) void flash_mfma_kernel(
    const f16* __restrict__ Qh, const f16* __restrict__ Kh, const f16* __restrict__ Vt,
    f16* __restrict__ Op, float* __restrict__ Mst, float* __restrict__ Lst)
{
    const int t  = threadIdx.x;
    const int wv = t >> 6;         // 0..3
    const int l  = t & 63;
    const int ln = l & 31;
    const int g  = l >> 5;

    // XCD swizzle: 2 (b,split) KV streams per XCD, 32 q-tile blocks per stream.
    const int flat  = blockIdx.x;        // 0..511
    const int xcd   = flat & 7;
    const int idx   = flat >> 3;         // 0..63
    const int bs    = xcd * 2 + (idx & 1);   // 0..15
    const int qt    = idx >> 1;          // 0..31
    const int b     = bs >> 2;
    const int split = bs & 3;
    const int qrow  = qt * 128 + wv * 32 + ln;

    __shared__ char ldsK[2 * 16384];   // [buf][32 key-rows x 512B], ^(row&15)
    __shared__ char ldsV[2 * 16384];   // [buf][64 rows x 256B] 4ch/row, ^(R&3)

    // ---- Q fragments (register-resident) ----
    f16x8 qf[16];
    {
        const f16* Qb = Qh + ((size_t)b * NN + qrow) * NC;
        #pragma unroll
        for (int cs = 0; cs < 16; ++cs)
            qf[cs] = *(const f16x8*)(Qb + cs * 16 + 8 * g);
    }

    f32x16 o[8];
    #pragma unroll
    for (int ct = 0; ct < 8; ++ct)
        #pragma unroll
        for (int r = 0; r < 16; ++r) o[ct][r] = 0.0f;

    float mrun = -1e30f, lrun = 0.0f;   // lrun = per-lane partial (merged at end)
    const int key_base = split * KRANGE;
    const f16* KhB = Kh + (size_t)b * NN * NC;
    const f16* VtB = Vt + (size_t)b * NC * NN;

    // 8 DMA instrs / wave / chunk (1KB each) — verbatim R5 lane maps
#define DMA(CH, BUF) do {                                                            \
        const int key0_ = key_base + (CH) * 32;                                      \
        _Pragma("unroll")                                                            \
        for (int j = 0; j < 4; ++j) {                                                \
            const int r2  = wv * 4 + j;                                              \
            const int row = r2 * 2 + (l >> 5);                                       \
            const int u   = (l & 31) ^ (row & 15);                                   \
            load_lds16(KhB + (size_t)(key0_ + row) * NC + u * 8,                     \
                       ldsK + (BUF) * 16384 + r2 * 1024);                            \
        }                                                                            \
        _Pragma("unroll")                                                            \
        for (int j = 0; j < 4; ++j) {                                                \
            const int i  = wv * 4 + j;                                               \
            const int R  = i * 4 + (l >> 4);                                         \
            const int c  = R * 4 + ((l & 15) >> 2);                                  \
            const int kg = (l & 3) ^ (R & 3);                                        \
            load_lds16(VtB + (size_t)c * NN + key0_ + kg * 8,                        \
                       ldsV + (BUF) * 16384 + i * 1024);                             \
        }                                                                            \
    } while (0)

    DMA(0, 0);

    for (int ch = 0; ch < NCHUNK; ++ch) {
        const int cb = ch & 1;
        if (ch + 1 < NCHUNK) {
            DMA(ch + 1, cb ^ 1);
            asm volatile("s_waitcnt vmcnt(8)" ::: "memory");   // chunk ch landed
        } else {
            asm volatile("s_waitcnt vmcnt(0)" ::: "memory");
        }
        __builtin_amdgcn_s_barrier();   // all waves' DMA landed

        const char* K0 = ldsK + cb * 16384;
        const char* V0 = ldsV + cb * 16384;

        // ---- S^T = K . Q^T : TWO independent 8-deep MFMA chains ----
        f32x16 sa, sb;
        #pragma unroll
        for (int r = 0; r < 16; ++r) { sa[r] = 0.0f; sb[r] = 0.0f; }
        __builtin_amdgcn_s_setprio(1);
        #pragma unroll
        for (int cs = 0; cs < 8; ++cs) {
            const int colA = ((cs * 2 + g) ^ (ln & 15)) * 16;
            const int colB = (((cs + 8) * 2 + g) ^ (ln & 15)) * 16;
            f16x8 a0 = *(const f16x8*)(K0 + ln * 512 + colA);
            f16x8 a1 = *(const f16x8*)(K0 + ln * 512 + colB);
            sa = __builtin_amdgcn_mfma_f32_32x32x16_f16(a0, qf[cs],     sa, 0, 0, 0);
            sb = __builtin_amdgcn_mfma_f32_32x32x16_f16(a1, qf[cs + 8], sb, 0, 0, 0);
        }
        __builtin_amdgcn_s_setprio(0);

        // ---- merge chains + online softmax (exp2 domain, defer THR=12) ----
        float sv[16];
        #pragma unroll
        for (int r = 0; r < 16; ++r) sv[r] = sa[r] + sb[r];

        float tm[16];
        #pragma unroll
        for (int r = 0; r < 16; ++r) tm[r] = sv[r];
        #pragma unroll
        for (int st = 8; st >= 1; st >>= 1)
            #pragma unroll
            for (int r = 0; r < st; ++r) tm[r] = fmaxf(tm[r], tm[r + st]);
        float mt = fmaxf(tm[0], __shfl_xor(tm[0], 32));

        if (!__all(mt <= mrun + 12.0f)) {
            const float mnew  = fmaxf(mrun, mt);
            const float alpha = exp2f(mrun - mnew);
            #pragma unroll
            for (int ct = 0; ct < 8; ++ct)
                #pragma unroll
                for (int r = 0; r < 16; ++r) o[ct][r] *= alpha;
            lrun *= alpha;
            mrun  = mnew;
        }

        float ps = 0.0f;
        f16x8 pf[2];   // S^T D-regs map 1:1 onto PV B-frag layout
        #pragma unroll
        for (int r = 0; r < 16; ++r) {
            const float e0 = exp2f(sv[r] - mrun);
            ps += e0;
            pf[r >> 3][r & 7] = (f16)e0;
        }
        lrun += ps;   // per-lane partial; merged once in epilogue

        // ---- O^T += V^T . P^T ----
        __builtin_amdgcn_s_setprio(1);
        #pragma unroll
        for (int ct = 0; ct < 8; ++ct) {
            const int c    = ct * 32 + ln;
            const int base = (c >> 2) * 256 + (c & 3) * 64;
            const int rsw  = (c >> 2) & 3;
            #pragma unroll
            for (int s = 0; s < 2; ++s) {
                f16x8 va = *(const f16x8*)(V0 + base + (((s * 2 + g) ^ rsw) * 16));
                o[ct] = __builtin_amdgcn_mfma_f32_32x32x16_f16(va, pf[s], o[ct], 0, 0, 0);
            }
        }
        __builtin_amdgcn_s_setprio(0);

        __builtin_amdgcn_s_barrier();   // reads done -> next iter may overwrite buf
    }
#undef DMA

    // ---- epilogue: merge lrun halves, store normalized partial + stats ----
    lrun += __shfl_xor(lrun, 32);
    const float invl = 1.0f / lrun;
    #pragma unroll
    for (int ct = 0; ct < 8; ++ct)
        #pragma unroll
        for (int r = 0; r < 16; ++r) {
            const int c = ct * 32 + (r & 3) + 8 * (r >> 2) + 4 * g;
            Op[((size_t)(split * NB + b) * NC + c) * NN + qrow] = (f16)(o[ct][r] * invl);
        }
    if (g == 0) {
        Mst[(split * NB + b) * NN + qrow] = mrun;
        Lst[(split * NB + b) * NN + qrow] = lrun;
    }
}

// ---------------- Kernel 3: combine kv-split partials ----------------
__global__ __launch_bounds__(256) void combine_kernel(
    const f16* __restrict__ Op, const float* __restrict__ Mst, const float* __restrict__ Lst,
    float* __restrict__ out)
{
    const int t = threadIdx.x;
    const int b = blockIdx.y;
    const int n = blockIdx.x * 64 + (t & 63);

    float w[KVSPLIT];
    float mm = -1e30f;
    #pragma unroll
    for (int s = 0; s < KVSPLIT; ++s) {
        w[s] = Mst[(s * NB + b) * NN + n];
        mm = fmaxf(mm, w[s]);
    }
    float tot = 0.0f;
    #pragma unroll
    for (int s = 0; s < KVSPLIT; ++s) {
        w[s] = exp2f(w[s] - mm) * Lst[(s * NB + b) * NN + n];
        tot += w[s];
    }
    const float inv = 1.0f / tot;
    #pragma unroll
    for (int s = 0; s < KVSPLIT; ++s) w[s] *= inv;

    for (int c = (t >> 6); c < NC; c += 4) {
        float acc = 0.0f;
        #pragma unroll
        for (int s = 0; s < KVSPLIT; ++s)
            acc += w[s] * (float)Op[((size_t)(s * NB + b) * NC + c) * NN + n];
        out[((size_t)b * NC + c) * NN + n] = acc;
    }
}

extern "C" void kernel_launch(void* const* d_in, const int* in_sizes, int n_in,
                              void* d_out, int out_size, void* d_ws, size_t ws_size,
                              hipStream_t stream)
{
    const float* x  = (const float*)d_in[0];
    const float* Wq = (const float*)d_in[1];
    const float* Wk = (const float*)d_in[2];
    const float* Wv = (const float*)d_in[3];
    const float* bq = (const float*)d_in[4];
    const float* bk = (const float*)d_in[5];
    const float* bv = (const float*)d_in[6];
    float* out = (float*)d_out;

    // Workspace layout (~57 MB)
    f16* Qh = (f16*)d_ws;                                       // 8 MB
    f16* Kh = Qh + (size_t)NB * NN * NC;                        // 8 MB
    f16* Vt = Kh + (size_t)NB * NN * NC;                        // 8 MB
    f16* Op = Vt + (size_t)NB * NN * NC;                        // 32 MB
    float* Mst = (float*)(Op + (size_t)KVSPLIT * NB * NC * NN); // 256 KB
    float* Lst = Mst + (size_t)KVSPLIT * NB * NN;               // 256 KB
    f16*  Wh  = (f16*)(Lst + (size_t)KVSPLIT * NB * NN);        // 384 KB

    wcvt_kernel<<<768, 256, 0, stream>>>(Wq, Wk, Wv, Wh);
    qkv_mfma_kernel<<<dim3(NN / 64, NB), 256, 0, stream>>>(
        x, Wh, bq, bk, bv, Qh, Kh, Vt);
    flash_mfma_kernel<<<512, 256, 0, stream>>>(Qh, Kh, Vt, Op, Mst, Lst);
    combine_kernel<<<dim3(NN / 64, NB), 256, 0, stream>>>(Op, Mst, Lst, out);
}

// Round 10
// 153.908 us; speedup vs baseline: 2.0198x; 1.0894x over previous
//
#include <hip/hip_runtime.h>

// CNN self-attention: B=4, C=256, H=W=64 -> N=4096.
// Round 10: R4 flash structure (512-thr, 1 block/CU, 16x64-key chunks, counted
//           vmcnt(8) dbuf) + conflict-free LDS: K granule ^(row&15) (R5-proven),
//           V 256B-row 2ch layout granule ^(R&7). exp2-domain softmax (Q
//           pre-scaled log2e), defer-rescale THR=12, per-lane lrun.
// Workspace: Qh,Kh,Vt f16 (24MB) + Op f16 (32MB) + stats (512KB) + Wh (384KB).

typedef _Float16 f16;
typedef f16 f16x4 __attribute__((ext_vector_type(4)));
typedef f16 f16x8 __attribute__((ext_vector_type(8)));
typedef float f32x16 __attribute__((ext_vector_type(16)));

#define NB 4
#define NC 256
#define NN 4096
#define KVSPLIT 4
#define KRANGE (NN / KVSPLIT)   // 1024 keys per split
#define NCHUNK (KRANGE / 64)    // 16 chunks of 64 keys

typedef const __attribute__((address_space(1))) void* gas_t;
typedef __attribute__((address_space(3))) void* las_t;

__device__ __forceinline__ void load_lds16(const void* g, void* l) {
    // async global->LDS DMA: LDS dest = uniform base + lane*16 (linear)
    __builtin_amdgcn_global_load_lds((gas_t)g, (las_t)l, 16, 0, 0);
}

// ---------------- Kernel 0: W fp32 -> f16 ----------------
__global__ __launch_bounds__(256) void wcvt_kernel(
    const float* __restrict__ Wq, const float* __restrict__ Wk,
    const float* __restrict__ Wv, f16* __restrict__ Wh)
{
    const int idx = blockIdx.x * 256 + threadIdx.x;   // grid = 768 blocks
    const float* s = (idx < 65536) ? Wq : (idx < 131072 ? Wk : Wv);
    Wh[idx] = (f16)s[idx & 65535];
}

// ---------------- Kernel 1: QKV projection via MFMA ----------------
// (validated rounds 2-9; Q scaled by log2(e) for exp2-domain softmax)
__global__ __launch_bounds__(256) void qkv_mfma_kernel(
    const float* __restrict__ x, const f16* __restrict__ Wh,
    const float* __restrict__ bq, const float* __restrict__ bk, const float* __restrict__ bv,
    f16* __restrict__ Qh, f16* __restrict__ Kh, f16* __restrict__ Vt)
{
    const int b  = blockIdx.y;
    const int n0 = blockIdx.x * 64;
    const int t  = threadIdx.x;
    const int wv = t >> 6, l = t & 63, ln = l & 31, g = l >> 5;

    __shared__ char xs[64 * 512];   // x^T tile [n][ci], swizzled granules
    __shared__ char st[32768];      // output staging

    {
        const int ci0 = t >> 4;
        const int nq  = (t & 15) * 4;
        for (int it = 0; it < 16; ++it) {
            const int ci = it * 16 + ci0;
            float v4[4];
            *(float4*)v4 = *(const float4*)(x + ((size_t)b * NC + ci) * NN + n0 + nq);
            const int gr = ci >> 3, lo = (ci & 7) * 2;
            #pragma unroll
            for (int j = 0; j < 4; ++j) {
                const int n = nq + j;
                *(f16*)(xs + n * 512 + ((gr ^ (n & 7)) * 16 + lo)) = (f16)v4[j];
            }
        }
    }
    __syncthreads();

    const int c0 = wv * 64;
    for (int m = 0; m < 3; ++m) {
        const f16*  W    = Wh + m * (NC * NC);
        const float* bias = (m == 0) ? bq : (m == 1 ? bk : bv);
        const float qs   = (m == 0) ? 1.44269504f : 1.0f;

        f32x16 acc[2][2];
        #pragma unroll
        for (int i = 0; i < 2; ++i)
            #pragma unroll
            for (int j = 0; j < 2; ++j)
                #pragma unroll
                for (int r = 0; r < 16; ++r) acc[i][j][r] = 0.0f;

        #pragma unroll
        for (int cs = 0; cs < 16; ++cs) {
            f16x8 a0 = *(const f16x8*)(W + (size_t)(c0 + ln) * NC + cs * 16 + 8 * g);
            f16x8 a1 = *(const f16x8*)(W + (size_t)(c0 + 32 + ln) * NC + cs * 16 + 8 * g);
            const int xb = (cs * 32 + g * 16) ^ ((ln & 7) << 4);
            f16x8 b0 = *(const f16x8*)(xs + ln * 512 + xb);
            f16x8 b1 = *(const f16x8*)(xs + (32 + ln) * 512 + xb);
            acc[0][0] = __builtin_amdgcn_mfma_f32_32x32x16_f16(a0, b0, acc[0][0], 0, 0, 0);
            acc[0][1] = __builtin_amdgcn_mfma_f32_32x32x16_f16(a0, b1, acc[0][1], 0, 0, 0);
            acc[1][0] = __builtin_amdgcn_mfma_f32_32x32x16_f16(a1, b0, acc[1][0], 0, 0, 0);
            acc[1][1] = __builtin_amdgcn_mfma_f32_32x32x16_f16(a1, b1, acc[1][1], 0, 0, 0);
        }

        __syncthreads();
        if (m < 2) {
            #pragma unroll
            for (int ct = 0; ct < 2; ++ct)
                #pragma unroll
                for (int nt = 0; nt < 2; ++nt)
                    #pragma unroll
                    for (int q = 0; q < 4; ++q) {
                        const int cb = c0 + ct * 32 + 8 * q + 4 * g;
                        f16x4 pk;
                        #pragma unroll
                        for (int j = 0; j < 4; ++j)
                            pk[j] = (f16)((acc[ct][nt][q * 4 + j] + bias[cb + j]) * qs);
                        const int n  = nt * 32 + ln;
                        const int g8 = cb >> 3;
                        *(f16x4*)(st + n * 512 + ((g8 ^ (n & 7)) * 16 + (cb & 7) * 2)) = pk;
                    }
            __syncthreads();
            f16* dst = (m == 0) ? Qh : Kh;
            const int gi  = t & 31;
            const int nb8 = (t >> 5) * 8;
            #pragma unroll
            for (int k = 0; k < 8; ++k) {
                const int n = nb8 + k;
                const uint4 d = *(const uint4*)(st + n * 512 + ((gi ^ (n & 7)) << 4));
                *(uint4*)(dst + ((size_t)b * NN + n0 + n) * NC + gi * 8) = d;
            }
        } else {
            #pragma unroll
            for (int ct = 0; ct < 2; ++ct)
                #pragma unroll
                for (int nt = 0; nt < 2; ++nt) {
                    const int n  = nt * 32 + ln;
                    const int pn = (n & ~15) | (n & 3) | ((n & 8) >> 1) | ((n & 4) << 1);
                    #pragma unroll
                    for (int r = 0; r < 16; ++r) {
                        const int c = c0 + ct * 32 + (r & 3) + 8 * (r >> 2) + 4 * g;
                        *(f16*)(st + c * 128 + ((pn * 2) ^ ((c & 7) << 4))) =
                            (f16)(acc[ct][nt][r] + bias[c]);
                    }
                }
            __syncthreads();
            #pragma unroll
            for (int ci = 0; ci < 8; ++ci) {
                const int c = ci * 32 + (t >> 3);
                const int s = t & 7;
                const uint4 d = *(const uint4*)(st + c * 128 + ((s ^ (c & 7)) << 4));
                *(uint4*)(Vt + ((size_t)b * NC + c) * NN + n0 + s * 8) = d;
            }
        }
    }
}

// ---------------- Kernel 2: MFMA flash attention (R4 + conflict-free LDS) ----
// 256 blocks x 512 threads = 1 block/CU, 8 waves, 128KB LDS.
// Per chunk: issue DMA(ch+1) -> vmcnt(8) [FIFO: chunk ch landed] -> s_barrier
// -> QK -> SM -> PV -> s_barrier.
// K LDS: [64 key-rows x 512B], granule ^(row&15). V LDS: [128 rows x 256B],
// row R = channels {2R, 2R+1} x 64 keys, granule (8*(c&1) + (oct ^ (R&7))).
__global__ __launch_bounds__(512, 2) void flash_mfma_kernel(
    const f16* __restrict__ Qh, const f16* __restrict__ Kh, const f16* __restrict__ Vt,
    f16* __restrict__ Op, float* __restrict__ Mst, float* __restrict__ Lst)
{
    const int t  = threadIdx.x;
    const int wv = t >> 6;
    const int l  = t & 63;
    const int ln = l & 31;
    const int g  = l >> 5;

    // XCD swizzle: 16 q-tile blocks sharing one (b,split) KV stream per XCD.
    const int flat  = blockIdx.x;       // 0..255
    const int xcd   = flat & 7;
    const int slot  = flat >> 3;        // 0..31
    const int bs    = xcd * 2 + (slot & 1);   // 0..15
    const int qt    = slot >> 1;        // 0..15
    const int b     = bs >> 2;
    const int split = bs & 3;
    const int qrow  = qt * 256 + wv * 32 + ln;

    __shared__ char ldsK[2 * 32768];   // [buf][64 key-rows x 512B]
    __shared__ char ldsV[2 * 32768];   // [buf][128 rows x 256B]

    // ---- Q fragments (register-resident) ----
    f16x8 qf[16];
    {
        const f16* Qb = Qh + ((size_t)b * NN + qrow) * NC;
        #pragma unroll
        for (int cs = 0; cs < 16; ++cs)
            qf[cs] = *(const f16x8*)(Qb + cs * 16 + 8 * g);
    }

    f32x16 o[8];
    #pragma unroll
    for (int ct = 0; ct < 8; ++ct)
        #pragma unroll
        for (int r = 0; r < 16; ++r) o[ct][r] = 0.0f;

    float mrun = -1e30f, lrun = 0.0f;   // lrun = per-lane partial
    const int key_base = split * KRANGE;
    const f16* KhB = Kh + (size_t)b * NN * NC;
    const f16* VtB = Vt + (size_t)b * NC * NN;

    // 8 DMA instrs / wave / chunk: 4 x K (2 key-rows of 512B each),
    //                              4 x V (4 rows of 256B each)
#define DMA(CH, BUF) do {                                                            \
        const int key0_ = key_base + (CH) * 64;                                      \
        _Pragma("unroll")                                                            \
        for (int j = 0; j < 4; ++j) {                                                \
            const int ki  = wv * 4 + j;                                              \
            const int row = ki * 2 + (l >> 5);                                       \
            const int u   = (l & 31) ^ (row & 15);                                   \
            load_lds16(KhB + (size_t)(key0_ + row) * NC + u * 8,                     \
                       ldsK + (BUF) * 32768 + ki * 1024);                            \
        }                                                                            \
        _Pragma("unroll")                                                            \
        for (int j = 0; j < 4; ++j) {                                                \
            const int vi = wv * 4 + j;                                               \
            const int R  = vi * 4 + (l >> 4);                                        \
            const int c  = R * 2 + ((l & 15) >> 3);                                  \
            const int k8 = (l & 7) ^ (R & 7);                                        \
            load_lds16(VtB + (size_t)c * NN + key0_ + k8 * 8,                        \
                       ldsV + (BUF) * 32768 + vi * 1024);                            \
        }                                                                            \
    } while (0)

    DMA(0, 0);

    for (int ch = 0; ch < NCHUNK; ++ch) {
        const int cb = ch & 1;
        if (ch + 1 < NCHUNK) {
            DMA(ch + 1, cb ^ 1);
            asm volatile("s_waitcnt vmcnt(8)" ::: "memory");   // chunk ch landed
        } else {
            asm volatile("s_waitcnt vmcnt(0)" ::: "memory");
        }
        __builtin_amdgcn_s_barrier();   // all waves' DMA landed

        const char* K0 = ldsK + cb * 32768;
        const char* V0 = ldsV + cb * 32768;

        // ---- S^T = K . Q^T : two 32-key tiles (s0/s1 = natural 2-chain ILP) ----
        f32x16 s0, s1;
        #pragma unroll
        for (int r = 0; r < 16; ++r) { s0[r] = 0.0f; s1[r] = 0.0f; }
        const int ksw = (ln & 15) << 4;
        __builtin_amdgcn_s_setprio(1);
        #pragma unroll
        for (int cs = 0; cs < 16; ++cs) {
            const int col = ((cs * 2 + g) << 4) ^ ksw;
            f16x8 a0 = *(const f16x8*)(K0 + ln * 512 + col);
            f16x8 a1 = *(const f16x8*)(K0 + (32 + ln) * 512 + col);
            s0 = __builtin_amdgcn_mfma_f32_32x32x16_f16(a0, qf[cs], s0, 0, 0, 0);
            s1 = __builtin_amdgcn_mfma_f32_32x32x16_f16(a1, qf[cs], s1, 0, 0, 0);
        }
        __builtin_amdgcn_s_setprio(0);

        // ---- online softmax (exp2 domain, defer-rescale THR=12) ----
        float mt = fmaxf(s0[0], s1[0]);
        #pragma unroll
        for (int r = 1; r < 16; ++r) mt = fmaxf(mt, fmaxf(s0[r], s1[r]));
        mt = fmaxf(mt, __shfl_xor(mt, 32));
        if (!__all(mt <= mrun + 12.0f)) {
            const float mnew  = fmaxf(mrun, mt);
            const float alpha = exp2f(mrun - mnew);
            #pragma unroll
            for (int ct = 0; ct < 8; ++ct)
                #pragma unroll
                for (int r = 0; r < 16; ++r) o[ct][r] *= alpha;
            lrun *= alpha;
            mrun  = mnew;
        }

        float ps = 0.0f;
        f16x8 pf[4];   // S^T D-regs map 1:1 onto PV B-frag layout
        #pragma unroll
        for (int r = 0; r < 16; ++r) {
            const float e0 = exp2f(s0[r] - mrun);
            const float e1 = exp2f(s1[r] - mrun);
            ps += e0 + e1;
            pf[r >> 3][r & 7]       = (f16)e0;
            pf[2 + (r >> 3)][r & 7] = (f16)e1;
        }
        lrun += ps;   // per-lane partial; merged once in epilogue

        // ---- O^T += V^T . P^T ----
        __builtin_amdgcn_s_setprio(1);
        #pragma unroll
        for (int ct = 0; ct < 8; ++ct) {
            const int c    = ct * 32 + ln;
            const int R    = c >> 1;
            const int base = R * 256 + (c & 1) * 128;
            const int rsw  = R & 7;
            #pragma unroll
            for (int s = 0; s < 4; ++s) {
                f16x8 va = *(const f16x8*)(V0 + base + (((s * 2 + g) ^ rsw) << 4));
                o[ct] = __builtin_amdgcn_mfma_f32_32x32x16_f16(va, pf[s], o[ct], 0, 0, 0);
            }
        }
        __builtin_amdgcn_s_setprio(0);

        __builtin_amdgcn_s_barrier();   // reads done -> next iter may overwrite buf
    }
#undef DMA

    // ---- epilogue: merge lrun halves, store normalized partial + stats ----
    lrun += __shfl_xor(lrun, 32);
    const float invl = 1.0f / lrun;
    #pragma unroll
    for (int ct = 0; ct < 8; ++ct)
        #pragma unroll
        for (int r = 0; r < 16; ++r) {
            const int c = ct * 32 + (r & 3) + 8 * (r >> 2) + 4 * g;
            Op[((size_t)(split * NB + b) * NC + c) * NN + qrow] = (f16)(o[ct][r] * invl);
        }
    if (g == 0) {
        Mst[(split * NB + b) * NN + qrow] = mrun;
        Lst[(split * NB + b) * NN + qrow] = lrun;
    }
}

// ---------------- Kernel 3: combine kv-split partials (log2-domain m) --------
__global__ __launch_bounds__(256) void combine_kernel(
    const f16* __restrict__ Op, const float* __restrict__ Mst, const float* __restrict__ Lst,
    float* __restrict__ out)
{
    const int t = threadIdx.x;
    const int b = blockIdx.y;
    const int n = blockIdx.x * 64 + (t & 63);

    float w[KVSPLIT];
    float mm = -1e30f;
    #pragma unroll
    for (int s = 0; s < KVSPLIT; ++s) {
        w[s] = Mst[(s * NB + b) * NN + n];
        mm = fmaxf(mm, w[s]);
    }
    float tot = 0.0f;
    #pragma unroll
    for (int s = 0; s < KVSPLIT; ++s) {
        w[s] = exp2f(w[s] - mm) * Lst[(s * NB + b) * NN + n];
        tot += w[s];
    }
    const float inv = 1.0f / tot;
    #pragma unroll
    for (int s = 0; s < KVSPLIT; ++s) w[s] *= inv;

    for (int c = (t >> 6); c < NC; c += 4) {
        float acc = 0.0f;
        #pragma unroll
        for (int s = 0; s < KVSPLIT; ++s)
            acc += w[s] * (float)Op[((size_t)(s * NB + b) * NC + c) * NN + n];
        out[((size_t)b * NC + c) * NN + n] = acc;
    }
}

extern "C" void kernel_launch(void* const* d_in, const int* in_sizes, int n_in,
                              void* d_out, int out_size, void* d_ws, size_t ws_size,
                              hipStream_t stream)
{
    const float* x  = (const float*)d_in[0];
    const float* Wq = (const float*)d_in[1];
    const float* Wk = (const float*)d_in[2];
    const float* Wv = (const float*)d_in[3];
    const float* bq = (const float*)d_in[4];
    const float* bk = (const float*)d_in[5];
    const float* bv = (const float*)d_in[6];
    float* out = (float*)d_out;

    // Workspace layout (~57 MB)
    f16* Qh = (f16*)d_ws;                                       // 8 MB
    f16* Kh = Qh + (size_t)NB * NN * NC;                        // 8 MB
    f16* Vt = Kh + (size_t)NB * NN * NC;                        // 8 MB
    f16* Op = Vt + (size_t)NB * NN * NC;                        // 32 MB
    float* Mst = (float*)(Op + (size_t)KVSPLIT * NB * NC * NN); // 256 KB
    float* Lst = Mst + (size_t)KVSPLIT * NB * NN;               // 256 KB
    f16*  Wh  = (f16*)(Lst + (size_t)KVSPLIT * NB * NN);        // 384 KB

    wcvt_kernel<<<768, 256, 0, stream>>>(Wq, Wk, Wv, Wh);
    qkv_mfma_kernel<<<dim3(NN / 64, NB), 256, 0, stream>>>(
        x, Wh, bq, bk, bv, Qh, Kh, Vt);
    flash_mfma_kernel<<<256, 512, 0, stream>>>(Qh, Kh, Vt, Op, Mst, Lst);
    combine_kernel<<<dim3(NN / 64, NB), 256, 0, stream>>>(Op, Mst, Lst, out);
}

// Round 11
// 132.230 us; speedup vs baseline: 2.3509x; 1.1639x over previous
//
#include <hip/hip_runtime.h>

// CNN self-attention: B=4, C=256, H=W=64 -> N=4096.
// Round 11: R4 (best-known: flash 101.7us) with exactly two diffs:
//   (1) single-barrier chunk loop: [vmcnt(0); s_barrier; sched_barrier;
//       DMA(ch+1 -> buf^1); compute(buf)] — write of buf^1 is after the
//       barrier; last read of buf^1 (compute ch-1) is before it. 16 drains
//       instead of 32, and ch+1's loads hide under the whole compute phase.
//   (2) per-lane partial lrun (no per-chunk cross-half shuffle; merged once
//       in the epilogue). Everything else byte-for-byte R4.
// Workspace: Qh,Kh,Vt f16 (24MB) + Op f16 (32MB) + stats (512KB) + Wh (384KB).

typedef _Float16 f16;
typedef f16 f16x4 __attribute__((ext_vector_type(4)));
typedef f16 f16x8 __attribute__((ext_vector_type(8)));
typedef float f32x16 __attribute__((ext_vector_type(16)));

#define NB 4
#define NC 256
#define NN 4096
#define KVSPLIT 4
#define KRANGE (NN / KVSPLIT)   // 1024 keys per split
#define NCHUNK (KRANGE / 64)    // 16 chunks of 64 keys

typedef const __attribute__((address_space(1))) void* gas_t;
typedef __attribute__((address_space(3))) void* las_t;

__device__ __forceinline__ void load_lds16(const void* g, void* l) {
    // async global->LDS DMA: LDS dest = uniform base + lane*16 (linear)
    __builtin_amdgcn_global_load_lds((gas_t)g, (las_t)l, 16, 0, 0);
}

// ---------------- Kernel 0: W fp32 -> f16 ----------------
__global__ __launch_bounds__(256) void wcvt_kernel(
    const float* __restrict__ Wq, const float* __restrict__ Wk,
    const float* __restrict__ Wv, f16* __restrict__ Wh)
{
    const int idx = blockIdx.x * 256 + threadIdx.x;   // grid = 768 blocks
    const float* s = (idx < 65536) ? Wq : (idx < 131072 ? Wk : Wv);
    Wh[idx] = (f16)s[idx & 65535];
}

// ---------------- Kernel 1: QKV projection via MFMA ----------------
// (verbatim from R4 — validated)
__global__ __launch_bounds__(256) void qkv_mfma_kernel(
    const float* __restrict__ x, const f16* __restrict__ Wh,
    const float* __restrict__ bq, const float* __restrict__ bk, const float* __restrict__ bv,
    f16* __restrict__ Qh, f16* __restrict__ Kh, f16* __restrict__ Vt)
{
    const int b  = blockIdx.y;
    const int n0 = blockIdx.x * 64;
    const int t  = threadIdx.x;
    const int wv = t >> 6, l = t & 63, ln = l & 31, g = l >> 5;

    __shared__ char xs[64 * 512];   // x^T tile [n][ci], swizzled granules
    __shared__ char st[32768];      // output staging

    {
        const int ci0 = t >> 4;
        const int nq  = (t & 15) * 4;
        for (int it = 0; it < 16; ++it) {
            const int ci = it * 16 + ci0;
            float v4[4];
            *(float4*)v4 = *(const float4*)(x + ((size_t)b * NC + ci) * NN + n0 + nq);
            const int gr = ci >> 3, lo = (ci & 7) * 2;
            #pragma unroll
            for (int j = 0; j < 4; ++j) {
                const int n = nq + j;
                *(f16*)(xs + n * 512 + ((gr ^ (n & 7)) * 16 + lo)) = (f16)v4[j];
            }
        }
    }
    __syncthreads();

    const int c0 = wv * 64;
    for (int m = 0; m < 3; ++m) {
        const f16*  W    = Wh + m * (NC * NC);
        const float* bias = (m == 0) ? bq : (m == 1 ? bk : bv);

        f32x16 acc[2][2];
        #pragma unroll
        for (int i = 0; i < 2; ++i)
            #pragma unroll
            for (int j = 0; j < 2; ++j)
                #pragma unroll
                for (int r = 0; r < 16; ++r) acc[i][j][r] = 0.0f;

        #pragma unroll
        for (int cs = 0; cs < 16; ++cs) {
            f16x8 a0 = *(const f16x8*)(W + (size_t)(c0 + ln) * NC + cs * 16 + 8 * g);
            f16x8 a1 = *(const f16x8*)(W + (size_t)(c0 + 32 + ln) * NC + cs * 16 + 8 * g);
            const int xb = (cs * 32 + g * 16) ^ ((ln & 7) << 4);
            f16x8 b0 = *(const f16x8*)(xs + ln * 512 + xb);
            f16x8 b1 = *(const f16x8*)(xs + (32 + ln) * 512 + xb);
            acc[0][0] = __builtin_amdgcn_mfma_f32_32x32x16_f16(a0, b0, acc[0][0], 0, 0, 0);
            acc[0][1] = __builtin_amdgcn_mfma_f32_32x32x16_f16(a0, b1, acc[0][1], 0, 0, 0);
            acc[1][0] = __builtin_amdgcn_mfma_f32_32x32x16_f16(a1, b0, acc[1][0], 0, 0, 0);
            acc[1][1] = __builtin_amdgcn_mfma_f32_32x32x16_f16(a1, b1, acc[1][1], 0, 0, 0);
        }

        __syncthreads();
        if (m < 2) {
            #pragma unroll
            for (int ct = 0; ct < 2; ++ct)
                #pragma unroll
                for (int nt = 0; nt < 2; ++nt)
                    #pragma unroll
                    for (int q = 0; q < 4; ++q) {
                        const int cb = c0 + ct * 32 + 8 * q + 4 * g;
                        f16x4 pk;
                        #pragma unroll
                        for (int j = 0; j < 4; ++j)
                            pk[j] = (f16)(acc[ct][nt][q * 4 + j] + bias[cb + j]);
                        const int n  = nt * 32 + ln;
                        const int g8 = cb >> 3;
                        *(f16x4*)(st + n * 512 + ((g8 ^ (n & 7)) * 16 + (cb & 7) * 2)) = pk;
                    }
            __syncthreads();
            f16* dst = (m == 0) ? Qh : Kh;
            const int gi  = t & 31;
            const int nb8 = (t >> 5) * 8;
            #pragma unroll
            for (int k = 0; k < 8; ++k) {
                const int n = nb8 + k;
                const uint4 d = *(const uint4*)(st + n * 512 + ((gi ^ (n & 7)) << 4));
                *(uint4*)(dst + ((size_t)b * NN + n0 + n) * NC + gi * 8) = d;
            }
        } else {
            #pragma unroll
            for (int ct = 0; ct < 2; ++ct)
                #pragma unroll
                for (int nt = 0; nt < 2; ++nt) {
                    const int n  = nt * 32 + ln;
                    const int pn = (n & ~15) | (n & 3) | ((n & 8) >> 1) | ((n & 4) << 1);
                    #pragma unroll
                    for (int r = 0; r < 16; ++r) {
                        const int c = c0 + ct * 32 + (r & 3) + 8 * (r >> 2) + 4 * g;
                        *(f16*)(st + c * 128 + ((pn * 2) ^ ((c & 7) << 4))) =
                            (f16)(acc[ct][nt][r] + bias[c]);
                    }
                }
            __syncthreads();
            #pragma unroll
            for (int ci = 0; ci < 8; ++ci) {
                const int c = ci * 32 + (t >> 3);
                const int s = t & 7;
                const uint4 d = *(const uint4*)(st + c * 128 + ((s ^ (c & 7)) << 4));
                *(uint4*)(Vt + ((size_t)b * NC + c) * NN + n0 + s * 8) = d;
            }
        }
    }
}

// ---------------- Kernel 2: MFMA flash attention ----------------
// 256 blocks x 512 threads = 1 block/CU, 8 waves, 128KB LDS (R4 structure).
// Per chunk: vmcnt(0) [chunk ch landed — issued a full compute-phase ago] ->
// s_barrier -> sched_barrier -> DMA(ch+1 -> buf^1) -> QK -> SM -> PV.
// Safety: buf^1's last read was compute(ch-1), before this barrier in every
// wave's program order; this chunk's reads (buf) are disjoint from the write.
__global__ __launch_bounds__(512, 2) void flash_mfma_kernel(
    const f16* __restrict__ Qh, const f16* __restrict__ Kh, const f16* __restrict__ Vt,
    f16* __restrict__ Op, float* __restrict__ Mst, float* __restrict__ Lst)
{
    const int t  = threadIdx.x;
    const int wv = t >> 6;
    const int l  = t & 63;
    const int ln = l & 31;
    const int g  = l >> 5;

    // XCD swizzle: 16 q-tile blocks sharing one (b,split) KV stream per XCD.
    const int flat  = blockIdx.x;       // 0..255
    const int xcd   = flat & 7;
    const int slot  = flat >> 3;        // 0..31
    const int bs    = xcd * 2 + (slot & 1);   // 0..15
    const int qt    = slot >> 1;        // 0..15
    const int b     = bs >> 2;
    const int split = bs & 3;
    const int qrow  = qt * 256 + wv * 32 + ln;

    __shared__ char ldsK[2 * 32768];   // [buf][64 key-rows x 512B]
    __shared__ char ldsV[2 * 32768];   // [buf][256 ch-rows x 128B]

    // ---- Q fragments (register-resident) ----
    f16x8 qf[16];
    {
        const f16* Qb = Qh + ((size_t)b * NN + qrow) * NC;
        #pragma unroll
        for (int cs = 0; cs < 16; ++cs)
            qf[cs] = *(const f16x8*)(Qb + cs * 16 + 8 * g);
    }

    f32x16 o[8];
    #pragma unroll
    for (int ct = 0; ct < 8; ++ct)
        #pragma unroll
        for (int r = 0; r < 16; ++r) o[ct][r] = 0.0f;

    float mrun = -1e30f, lrun = 0.0f;   // lrun = per-lane partial
    const int key_base = split * KRANGE;
    const f16* KhB = Kh + (size_t)b * NN * NC;
    const f16* VtB = Vt + (size_t)b * NC * NN;

    // 8 DMA instrs / wave / chunk (R4 lane maps, verbatim)
#define DMA(CH, BUF) do {                                                            \
        const int key0_ = key_base + (CH) * 64;                                      \
        _Pragma("unroll")                                                            \
        for (int j = 0; j < 4; ++j) {                                                \
            const int r2  = wv * 4 + j;                                              \
            const int row = r2 * 2 + (l >> 5);                                       \
            const int u   = (l & 31) ^ (row & 7);                                    \
            load_lds16(KhB + (size_t)(key0_ + row) * NC + u * 8,                     \
                       ldsK + (BUF) * 32768 + r2 * 1024);                            \
        }                                                                            \
        _Pragma("unroll")                                                            \
        for (int j = 0; j < 4; ++j) {                                                \
            const int c8 = wv * 4 + j;                                               \
            const int c  = c8 * 8 + (l >> 3);                                        \
            const int u  = (l & 7) ^ (c & 7);                                        \
            load_lds16(VtB + (size_t)c * NN + key0_ + u * 8,                         \
                       ldsV + (BUF) * 32768 + c8 * 1024);                            \
        }                                                                            \
    } while (0)

    DMA(0, 0);

    for (int ch = 0; ch < NCHUNK; ++ch) {
        const int cb = ch & 1;
        asm volatile("s_waitcnt vmcnt(0)" ::: "memory");   // chunk ch landed
        __builtin_amdgcn_s_barrier();                      // ... in all waves
        __builtin_amdgcn_sched_barrier(0);                 // pin ds_reads below
        if (ch + 1 < NCHUNK) DMA(ch + 1, cb ^ 1);          // hides under compute

        const char* K0 = ldsK + cb * 32768;
        const char* V0 = ldsV + cb * 32768;

        // ---- S^T = K . Q^T ----
        f32x16 s0, s1;
        #pragma unroll
        for (int r = 0; r < 16; ++r) { s0[r] = 0.0f; s1[r] = 0.0f; }
        const int ksw = (ln & 7) << 4;
        __builtin_amdgcn_s_setprio(1);
        #pragma unroll
        for (int cs = 0; cs < 16; ++cs) {
            const int col = (cs * 32 + g * 16) ^ ksw;
            f16x8 a0 = *(const f16x8*)(K0 + ln * 512 + col);
            f16x8 a1 = *(const f16x8*)(K0 + (32 + ln) * 512 + col);
            s0 = __builtin_amdgcn_mfma_f32_32x32x16_f16(a0, qf[cs], s0, 0, 0, 0);
            s1 = __builtin_amdgcn_mfma_f32_32x32x16_f16(a1, qf[cs], s1, 0, 0, 0);
        }
        __builtin_amdgcn_s_setprio(0);

        // ---- online softmax with defer-rescale (THR=8) ----
        float mt = fmaxf(s0[0], s1[0]);
        #pragma unroll
        for (int r = 1; r < 16; ++r) mt = fmaxf(mt, fmaxf(s0[r], s1[r]));
        mt = fmaxf(mt, __shfl_xor(mt, 32));
        if (!__all(mt <= mrun + 8.0f)) {
            const float mnew  = fmaxf(mrun, mt);
            const float alpha = __expf(mrun - mnew);
            #pragma unroll
            for (int ct = 0; ct < 8; ++ct)
                #pragma unroll
                for (int r = 0; r < 16; ++r) o[ct][r] *= alpha;
            lrun *= alpha;
            mrun  = mnew;
        }

        float ps = 0.0f;
        f16x8 pf[4];   // S^T D-regs map 1:1 onto PV B-frag layout
        #pragma unroll
        for (int r = 0; r < 16; ++r) {
            const float e0 = __expf(s0[r] - mrun);
            const float e1 = __expf(s1[r] - mrun);
            ps += e0 + e1;
            pf[r >> 3][r & 7]       = (f16)e0;
            pf[2 + (r >> 3)][r & 7] = (f16)e1;
        }
        lrun += ps;   // per-lane partial; merged once in epilogue

        // ---- O^T += V^T . P^T ----
        const int vsw = (ln & 7) << 4;
        __builtin_amdgcn_s_setprio(1);
        #pragma unroll
        for (int ct = 0; ct < 8; ++ct) {
            const int vrow = (ct * 32 + ln) * 128;
            #pragma unroll
            for (int s = 0; s < 4; ++s) {
                f16x8 va = *(const f16x8*)(V0 + vrow + ((s * 32 + g * 16) ^ vsw));
                o[ct] = __builtin_amdgcn_mfma_f32_32x32x16_f16(va, pf[s], o[ct], 0, 0, 0);
            }
        }
        __builtin_amdgcn_s_setprio(0);
    }
#undef DMA

    // ---- epilogue: merge lrun halves, store normalized partial + stats ----
    lrun += __shfl_xor(lrun, 32);
    const float invl = 1.0f / lrun;
    #pragma unroll
    for (int ct = 0; ct < 8; ++ct)
        #pragma unroll
        for (int r = 0; r < 16; ++r) {
            const int c = ct * 32 + (r & 3) + 8 * (r >> 2) + 4 * g;
            Op[((size_t)(split * NB + b) * NC + c) * NN + qrow] = (f16)(o[ct][r] * invl);
        }
    if (g == 0) {
        Mst[(split * NB + b) * NN + qrow] = mrun;
        Lst[(split * NB + b) * NN + qrow] = lrun;
    }
}

// ---------------- Kernel 3: combine kv-split partials ----------------
__global__ __launch_bounds__(256) void combine_kernel(
    const f16* __restrict__ Op, const float* __restrict__ Mst, const float* __restrict__ Lst,
    float* __restrict__ out)
{
    const int t = threadIdx.x;
    const int b = blockIdx.y;
    const int n = blockIdx.x * 64 + (t & 63);

    float w[KVSPLIT];
    float mm = -1e30f;
    #pragma unroll
    for (int s = 0; s < KVSPLIT; ++s) {
        w[s] = Mst[(s * NB + b) * NN + n];
        mm = fmaxf(mm, w[s]);
    }
    float tot = 0.0f;
    #pragma unroll
    for (int s = 0; s < KVSPLIT; ++s) {
        w[s] = __expf(w[s] - mm) * Lst[(s * NB + b) * NN + n];
        tot += w[s];
    }
    const float inv = 1.0f / tot;
    #pragma unroll
    for (int s = 0; s < KVSPLIT; ++s) w[s] *= inv;

    for (int c = (t >> 6); c < NC; c += 4) {
        float acc = 0.0f;
        #pragma unroll
        for (int s = 0; s < KVSPLIT; ++s)
            acc += w[s] * (float)Op[((size_t)(s * NB + b) * NC + c) * NN + n];
        out[((size_t)b * NC + c) * NN + n] = acc;
    }
}

extern "C" void kernel_launch(void* const* d_in, const int* in_sizes, int n_in,
                              void* d_out, int out_size, void* d_ws, size_t ws_size,
                              hipStream_t stream)
{
    const float* x  = (const float*)d_in[0];
    const float* Wq = (const float*)d_in[1];
    const float* Wk = (const float*)d_in[2];
    const float* Wv = (const float*)d_in[3];
    const float* bq = (const float*)d_in[4];
    const float* bk = (const float*)d_in[5];
    const float* bv = (const float*)d_in[6];
    float* out = (float*)d_out;

    // Workspace layout (~57 MB)
    f16* Qh = (f16*)d_ws;                                       // 8 MB
    f16* Kh = Qh + (size_t)NB * NN * NC;                        // 8 MB
    f16* Vt = Kh + (size_t)NB * NN * NC;                        // 8 MB
    f16* Op = Vt + (size_t)NB * NN * NC;                        // 32 MB
    float* Mst = (float*)(Op + (size_t)KVSPLIT * NB * NC * NN); // 256 KB
    float* Lst = Mst + (size_t)KVSPLIT * NB * NN;               // 256 KB
    f16*  Wh  = (f16*)(Lst + (size_t)KVSPLIT * NB * NN);        // 384 KB

    wcvt_kernel<<<768, 256, 0, stream>>>(Wq, Wk, Wv, Wh);
    qkv_mfma_kernel<<<dim3(NN / 64, NB), 256, 0, stream>>>(
        x, Wh, bq, bk, bv, Qh, Kh, Vt);
    flash_mfma_kernel<<<256, 512, 0, stream>>>(Qh, Kh, Vt, Op, Mst, Lst);
    combine_kernel<<<dim3(NN / 64, NB), 256, 0, stream>>>(Op, Mst, Lst, out);
}